// Round 3
// baseline (271.128 us; speedup 1.0000x reference)
//
#include <hip/hip_runtime.h>
#include <math.h>

// Problem constants
#define DMODEL 96
#define DIN    192
#define NST    16
#define RK     6
#define KDIR   4
#define LLEN   4096   // H*W
#define BB     2
#define BP_TOT 8192   // B*L
#define SCH    128    // scan chunks
#define TCH    32     // steps per chunk (L/SCH)

// ---------------------------------------------------------------------------
// K0: one-shot weight transposes for coalesced GEMM weight loads.
// WpT[c][e] (96x384), XpwT[d][r] (192x152), WoT[d][c] (192x96)
__global__ __launch_bounds__(256) void k_wtrans(const float* __restrict__ Wp,
                                                const float* __restrict__ xpw,
                                                const float* __restrict__ Wo,
                                                float* __restrict__ WpT,
                                                float* __restrict__ XpwT,
                                                float* __restrict__ WoT)
{
    int i = blockIdx.x * 256 + threadIdx.x;
    if (i < 384 * 96) { int e = i / 96, c = i % 96;  WpT [c * 384 + e] = Wp[i]; }
    if (i < 152 * 192){ int r = i / 192, d = i % 192; XpwT[d * 152 + r] = xpw[i]; }
    if (i < 96 * 192) { int c = i / 192, d = i % 192; WoT [d * 96  + c] = Wo[i]; }
}

// ---------------------------------------------------------------------------
// K1: in_proj  xz[bp,e] = sum_c x[bp,c] * Wp[e,c];  e<192 -> xi, e>=192 -> z
__global__ __launch_bounds__(192) void k_inproj(const float* __restrict__ x,
                                                const float* __restrict__ WpT,
                                                float* __restrict__ xi,
                                                float* __restrict__ z)
{
    __shared__ float xT[96 * 12];  // [c][pp], stride 12
    const int t  = threadIdx.x;
    const int p0 = blockIdx.x * 8;
    #pragma unroll
    for (int it = 0; it < 4; ++it) {
        int idx = t + it * 192;
        int c = idx % 96, pp = idx / 96;
        xT[c * 12 + pp] = x[(p0 + pp) * 96 + c];
    }
    __syncthreads();

    float acc0[8], acc1[8];
    #pragma unroll
    for (int i = 0; i < 8; ++i) { acc0[i] = 0.f; acc1[i] = 0.f; }
    #pragma unroll 4
    for (int k = 0; k < 96; ++k) {
        float w0 = WpT[k * 384 + t];
        float w1 = WpT[k * 384 + 192 + t];
        float4 a = *(const float4*)&xT[k * 12];
        float4 b = *(const float4*)&xT[k * 12 + 4];
        float xv[8] = {a.x, a.y, a.z, a.w, b.x, b.y, b.z, b.w};
        #pragma unroll
        for (int i = 0; i < 8; ++i) {
            acc0[i] += w0 * xv[i];
            acc1[i] += w1 * xv[i];
        }
    }
    #pragma unroll
    for (int i = 0; i < 8; ++i) {
        xi[(p0 + i) * 192 + t] = acc0[i];
        z [(p0 + i) * 192 + t] = acc1[i];
    }
}

// ---------------------------------------------------------------------------
// K2: depthwise 3x3 conv (SAME) + bias + SiLU.  (b,p,d) layout, coalesced in d.
__global__ __launch_bounds__(256) void k_conv(const float* __restrict__ xi,
                                              const float* __restrict__ cw,
                                              const float* __restrict__ cb,
                                              float* __restrict__ xc)
{
    int tid = blockIdx.x * 256 + threadIdx.x;  // BP_TOT*192 total
    int d  = tid % 192;
    int bp = tid / 192;
    int p  = bp & 4095;
    int b  = bp >> 12;
    int h  = p >> 6, w = p & 63;
    float s = cb[d];
    #pragma unroll
    for (int ky = 0; ky < 3; ++ky) {
        int hh = h + ky - 1;
        if (hh < 0 || hh >= 64) continue;
        #pragma unroll
        for (int kx = 0; kx < 3; ++kx) {
            int ww = w + kx - 1;
            if (ww < 0 || ww >= 64) continue;
            s += xi[((size_t)b * 4096 + hh * 64 + ww) * 192 + d] * cw[d * 9 + ky * 3 + kx];
        }
    }
    xc[tid] = s * (1.f / (1.f + __expf(-s)));  // SiLU
}

// ---------------------------------------------------------------------------
// K3: x_proj for all 4 directions at once. Weights transposed: XpwT[d][152].
__global__ __launch_bounds__(256) void k_xdbl(const float* __restrict__ xc,
                                              const float* __restrict__ XpwT,
                                              float* __restrict__ xdbl)
{
    __shared__ float xl[192 * 52];  // [c][pp], stride 52
    const int t  = threadIdx.x;
    const int p0 = blockIdx.x * 48;
    #pragma unroll
    for (int it = 0; it < 36; ++it) {
        int idx = t + it * 256;
        int c = idx % 192, pp = idx / 192;
        int bp = p0 + pp;
        xl[c * 52 + pp] = (bp < BP_TOT) ? xc[(size_t)bp * 192 + c] : 0.f;
    }
    __syncthreads();

    int g = t / 38, cq = t % 38;
    if (g >= 6) return;
    float acc[4][8];
    #pragma unroll
    for (int j = 0; j < 4; ++j)
        #pragma unroll
        for (int i = 0; i < 8; ++i) acc[j][i] = 0.f;

    #pragma unroll 2
    for (int k = 0; k < 192; ++k) {
        float4 a = *(const float4*)&xl[k * 52 + g * 8];
        float4 b = *(const float4*)&xl[k * 52 + g * 8 + 4];
        float xv[8] = {a.x, a.y, a.z, a.w, b.x, b.y, b.z, b.w};
        float4 w = *(const float4*)&XpwT[k * 152 + 4 * cq];
        #pragma unroll
        for (int i = 0; i < 8; ++i) {
            acc[0][i] += w.x * xv[i];
            acc[1][i] += w.y * xv[i];
            acc[2][i] += w.z * xv[i];
            acc[3][i] += w.w * xv[i];
        }
    }
    #pragma unroll
    for (int i = 0; i < 8; ++i) {
        int bp = p0 + g * 8 + i;
        if (bp < BP_TOT) {
            float4 v = make_float4(acc[0][i], acc[1][i], acc[2][i], acc[3][i]);
            *(float4*)&xdbl[(size_t)bp * 152 + 4 * cq] = v;
        }
    }
}

// ---------------------------------------------------------------------------
// scan-order -> position permutation (H=W=64)
__device__ __forceinline__ int perm_pos(int k, int l)
{
    if (k == 0) return l;
    if (k == 1) return ((l & 63) << 6) | (l >> 6);
    if (k == 2) return 4095 - l;
    int lr = 4095 - l;
    return ((lr & 63) << 6) | (lr >> 6);
}

__device__ __forceinline__ float softplus_fast(float x)
{
    float r = __logf(1.f + __expf(x));
    return (x > 15.f) ? x : r;
}

// binary power chain: aa[n] = e1^(n+1), depth 4
__device__ __forceinline__ void pow_chain(float e1, float* aa)
{
    float e2 = e1 * e1, e4 = e2 * e2, e8 = e4 * e4, e16 = e8 * e8;
    float e3 = e2 * e1, e5 = e4 * e1, e6 = e4 * e2, e7 = e4 * e3;
    aa[0] = e1;  aa[1] = e2;  aa[2] = e3;  aa[3] = e4;
    aa[4] = e5;  aa[5] = e6;  aa[6] = e7;  aa[7] = e8;
    aa[8] = e8 * e1;  aa[9] = e8 * e2;  aa[10] = e8 * e3;  aa[11] = e8 * e4;
    aa[12] = e8 * e5; aa[13] = e8 * e6; aa[14] = e8 * e7;  aa[15] = e16;
}

// ---------------------------------------------------------------------------
// K4: scan pass 1 — per-chunk local recurrence from h=0.
// Fast path (A[n] = (n+1)*A0): emits full local y (C·h_loc + D·u) via atomics,
// stores per-step cumulative-delta cd for pass 3's correction, plus h_end and
// prodA[n] = exp(A[n]*sum_delta). Slow path: only h_end/prodA (pass 3 replays).
__global__ __launch_bounds__(192) void k_scan1(const float* __restrict__ xc,
                                               const float* __restrict__ xdbl,
                                               const float* __restrict__ dtw,
                                               const float* __restrict__ dtb,
                                               const float* __restrict__ Alog,
                                               const float* __restrict__ Ds,
                                               float* __restrict__ hend,
                                               float* __restrict__ prodA,
                                               float* __restrict__ cdbuf,
                                               float* __restrict__ y)
{
    __shared__ float sm[TCH * 40];  // per step: B[0..15], C[16..31], dt[32..37]
    const int t   = threadIdx.x;
    const int blk = blockIdx.x;
    const int s = blk & (SCH - 1), k = (blk >> 7) & 3, b = blk >> 9;
    const int kd = k * 192 + t;
    const int l0 = s * TCH;

    const float* xdb = xdbl + (size_t)b * 4096 * 152 + k * 38;
    const float* xcb = xc   + (size_t)b * 4096 * 192;
    float* yb = y + (size_t)b * 4096 * 192;

    for (int idx = t; idx < TCH * 38; idx += 192) {
        int st = idx / 38, c = idx % 38;
        int gcol = (c < 32) ? (6 + c) : (c - 32);
        sm[st * 40 + c] = xdb[(size_t)perm_pos(k, l0 + st) * 152 + gcol];
    }

    const float A0 = -__expf(Alog[kd * 16]);
    bool fast = true;
    #pragma unroll
    for (int n = 1; n < 16; ++n) {
        float An = -__expf(Alog[kd * 16 + n]);
        fast = fast && (fabsf(An - (float)(n + 1) * A0) <= 1e-3f * fabsf(An));
    }
    float wdt[6];
    #pragma unroll
    for (int r = 0; r < 6; ++r) wdt[r] = dtw[kd * 6 + r];
    const float bias = dtb[kd];
    const float Dk   = Ds[kd];

    float h[16];
    #pragma unroll
    for (int n = 0; n < 16; ++n) h[n] = 0.f;
    float cd = 0.f;

    int allfast = __syncthreads_and((int)fast);  // also the staging barrier

    int p_cur = perm_pos(k, l0);
    float u = xcb[(size_t)p_cur * 192 + t];

    if (allfast) {
        for (int st = 0; st < TCH; ++st) {
            int p_next = (st + 1 < TCH) ? perm_pos(k, l0 + st + 1) : p_cur;
            float u_next = xcb[(size_t)p_next * 192 + t];
            const float* r = &sm[st * 40];
            float4 dq = *(const float4*)(r + 32);
            float xv = bias + dq.x * wdt[0] + dq.y * wdt[1] + dq.z * wdt[2]
                            + dq.w * wdt[3] + r[36] * wdt[4] + r[37] * wdt[5];
            float delta = softplus_fast(xv);
            cd += delta;
            cdbuf[((size_t)blk * TCH + st) * 192 + t] = cd;
            float du = delta * u;
            float aa[16];
            pow_chain(__expf(delta * A0), aa);
            float4 b0 = *(const float4*)(r), b1 = *(const float4*)(r + 4);
            float4 b2 = *(const float4*)(r + 8), b3 = *(const float4*)(r + 12);
            float4 c0 = *(const float4*)(r + 16), c1 = *(const float4*)(r + 20);
            float4 c2 = *(const float4*)(r + 24), c3 = *(const float4*)(r + 28);
            float bv[16] = {b0.x, b0.y, b0.z, b0.w, b1.x, b1.y, b1.z, b1.w,
                            b2.x, b2.y, b2.z, b2.w, b3.x, b3.y, b3.z, b3.w};
            float cv[16] = {c0.x, c0.y, c0.z, c0.w, c1.x, c1.y, c1.z, c1.w,
                            c2.x, c2.y, c2.z, c2.w, c3.x, c3.y, c3.z, c3.w};
            float acc = Dk * u;
            #pragma unroll
            for (int n = 0; n < 16; ++n) {
                h[n] = fmaf(h[n], aa[n], du * bv[n]);
                acc  = fmaf(h[n], cv[n], acc);
            }
            unsafeAtomicAdd(&yb[(size_t)p_cur * 192 + t], acc);
            u = u_next; p_cur = p_next;
        }
    } else {
        for (int st = 0; st < TCH; ++st) {
            int p_next = (st + 1 < TCH) ? perm_pos(k, l0 + st + 1) : p_cur;
            float u_next = xcb[(size_t)p_next * 192 + t];
            const float* r = &sm[st * 40];
            float xv = bias;
            #pragma unroll
            for (int j = 0; j < 6; ++j) xv += r[32 + j] * wdt[j];
            float delta = softplus_fast(xv);
            cd += delta;
            float du = delta * u;
            #pragma unroll
            for (int n = 0; n < 16; ++n) {
                float An = -__expf(Alog[kd * 16 + n]);
                h[n] = fmaf(h[n], __expf(delta * An), du * r[n]);
            }
            u = u_next; p_cur = p_next;
        }
    }

    size_t base = (size_t)blk * 3072 + t * 16;
    float ap[16];
    if (allfast) {
        pow_chain(__expf(cd * A0), ap);
    } else {
        #pragma unroll
        for (int n = 0; n < 16; ++n)
            ap[n] = __expf(-__expf(Alog[kd * 16 + n]) * cd);
    }
    #pragma unroll
    for (int i = 0; i < 4; ++i) {
        *(float4*)&hend [base + 4 * i] = make_float4(h[4*i], h[4*i+1], h[4*i+2], h[4*i+3]);
        *(float4*)&prodA[base + 4 * i] = make_float4(ap[4*i], ap[4*i+1], ap[4*i+2], ap[4*i+3]);
    }
}

// ---------------------------------------------------------------------------
// K5: scan pass 2 — serial composition over chunks per (b,k,d,n).
// Overwrites prodA with h_init per chunk.
__global__ __launch_bounds__(256) void k_scan2(const float* __restrict__ hend,
                                               float* __restrict__ prodA)
{
    int tid = blockIdx.x * 256 + threadIdx.x;  // 24576 lanes
    int n  = tid & 15;
    int d  = (tid >> 4) % 192;
    int bk = tid / (192 * 16);
    size_t base = (size_t)bk * SCH * 3072 + d * 16 + n;
    float carry = 0.f;
    for (int s = 0; s < SCH; ++s) {
        size_t a = base + (size_t)s * 3072;
        float pa = prodA[a];
        float he = hend[a];
        prodA[a] = carry;            // becomes h_init
        carry = fmaf(pa, carry, he);
    }
}

// ---------------------------------------------------------------------------
// K6: scan pass 3 — fast path: correction only, y += sum_n C[n]*h_init[n]*E^(n+1)
// with E = exp(cd*A0). Slow path: full replay.
__global__ __launch_bounds__(192) void k_scan3(const float* __restrict__ xc,
                                               const float* __restrict__ xdbl,
                                               const float* __restrict__ dtw,
                                               const float* __restrict__ dtb,
                                               const float* __restrict__ Alog,
                                               const float* __restrict__ Ds,
                                               const float* __restrict__ hinit,
                                               const float* __restrict__ cdbuf,
                                               float* __restrict__ y)
{
    __shared__ float sm[TCH * 40];
    const int t   = threadIdx.x;
    const int blk = blockIdx.x;
    const int s = blk & (SCH - 1), k = (blk >> 7) & 3, b = blk >> 9;
    const int kd = k * 192 + t;
    const int l0 = s * TCH;

    const float* xdb = xdbl + (size_t)b * 4096 * 152 + k * 38;
    float* yb = y + (size_t)b * 4096 * 192;

    const float A0 = -__expf(Alog[kd * 16]);
    bool fast = true;
    #pragma unroll
    for (int n = 1; n < 16; ++n) {
        float An = -__expf(Alog[kd * 16 + n]);
        fast = fast && (fabsf(An - (float)(n + 1) * A0) <= 1e-3f * fabsf(An));
    }
    int allfast = __syncthreads_and((int)fast);

    float hi[16];
    size_t hbase = (size_t)blk * 3072 + t * 16;
    #pragma unroll
    for (int i = 0; i < 4; ++i) {
        float4 v = *(const float4*)&hinit[hbase + 4 * i];
        hi[4*i] = v.x; hi[4*i+1] = v.y; hi[4*i+2] = v.z; hi[4*i+3] = v.w;
    }

    if (allfast) {
        if (s == 0) return;  // h_init == 0, correction vanishes
        // stage C columns only
        for (int idx = t; idx < TCH * 16; idx += 192) {
            int st = idx >> 4, c = idx & 15;
            sm[st * 16 + c] = xdb[(size_t)perm_pos(k, l0 + st) * 152 + 22 + c];
        }
        __syncthreads();
        float cd_next = cdbuf[((size_t)blk * TCH) * 192 + t];
        for (int st = 0; st < TCH; ++st) {
            float cdv = cd_next;
            if (st + 1 < TCH)
                cd_next = cdbuf[((size_t)blk * TCH + st + 1) * 192 + t];
            float aa[16];
            pow_chain(__expf(cdv * A0), aa);
            const float* r = &sm[st * 16];
            float corr = 0.f;
            #pragma unroll
            for (int n = 0; n < 16; ++n)
                corr = fmaf(aa[n] * hi[n], r[n], corr);
            unsafeAtomicAdd(&yb[(size_t)perm_pos(k, l0 + st) * 192 + t], corr);
        }
    } else {
        const float* xcb = xc + (size_t)b * 4096 * 192;
        float wdt[6];
        #pragma unroll
        for (int r = 0; r < 6; ++r) wdt[r] = dtw[kd * 6 + r];
        const float bias = dtb[kd];
        const float Dk   = Ds[kd];
        for (int idx = t; idx < TCH * 38; idx += 192) {
            int st = idx / 38, c = idx % 38;
            int gcol = (c < 32) ? (6 + c) : (c - 32);
            sm[st * 40 + c] = xdb[(size_t)perm_pos(k, l0 + st) * 152 + gcol];
        }
        __syncthreads();
        float h[16];
        #pragma unroll
        for (int n = 0; n < 16; ++n) h[n] = hi[n];
        int p_cur = perm_pos(k, l0);
        float u = xcb[(size_t)p_cur * 192 + t];
        for (int st = 0; st < TCH; ++st) {
            int p_next = (st + 1 < TCH) ? perm_pos(k, l0 + st + 1) : p_cur;
            float u_next = xcb[(size_t)p_next * 192 + t];
            const float* r = &sm[st * 40];
            float xv = bias;
            #pragma unroll
            for (int j = 0; j < 6; ++j) xv += r[32 + j] * wdt[j];
            float delta = softplus_fast(xv);
            float du = delta * u;
            float acc = Dk * u;
            #pragma unroll
            for (int n = 0; n < 16; ++n) {
                float An = -__expf(Alog[kd * 16 + n]);
                h[n] = fmaf(h[n], __expf(delta * An), du * r[n]);
                acc  = fmaf(h[n], r[16 + n], acc);
            }
            unsafeAtomicAdd(&yb[(size_t)p_cur * 192 + t], acc);
            u = u_next; p_cur = p_next;
        }
    }
}

// ---------------------------------------------------------------------------
// K7: LayerNorm(192) + out_norm affine + SiLU(z) gate
__global__ __launch_bounds__(192) void k_lngate(const float* __restrict__ y,
                                                const float* __restrict__ z,
                                                const float* __restrict__ onw,
                                                const float* __restrict__ onb,
                                                float* __restrict__ yg)
{
    const int t  = threadIdx.x;
    const int bp = blockIdx.x;
    float yv = y[(size_t)bp * 192 + t];
    float s1 = yv, s2 = yv * yv;
    #pragma unroll
    for (int off = 32; off; off >>= 1) {
        s1 += __shfl_xor(s1, off, 64);
        s2 += __shfl_xor(s2, off, 64);
    }
    __shared__ float rs[3], rq[3];
    int wv = t >> 6;
    if ((t & 63) == 0) { rs[wv] = s1; rq[wv] = s2; }
    __syncthreads();
    float tot  = rs[0] + rs[1] + rs[2];
    float totq = rq[0] + rq[1] + rq[2];
    float mean = tot * (1.f / 192.f);
    float var  = totq * (1.f / 192.f) - mean * mean;
    float rinv = rsqrtf(var + 1e-5f);
    float yn = (yv - mean) * rinv * onw[t] + onb[t];
    float zv = z[(size_t)bp * 192 + t];
    float sig = 1.f / (1.f + __expf(-zv));
    yg[(size_t)bp * 192 + t] = yn * (zv * sig);
}

// ---------------------------------------------------------------------------
// K8: out_proj  out[bp,c] = sum_d yg[bp,d] * Wo[c,d]; weights WoT[d][96]
__global__ __launch_bounds__(256) void k_outproj(const float* __restrict__ yg,
                                                 const float* __restrict__ WoT,
                                                 float* __restrict__ out)
{
    __shared__ float xl[192 * 44];
    const int t  = threadIdx.x;
    const int p0 = blockIdx.x * 40;
    #pragma unroll
    for (int it = 0; it < 30; ++it) {
        int idx = t + it * 256;
        int c = idx % 192, pp = idx / 192;
        int bp = p0 + pp;
        xl[c * 44 + pp] = (bp < BP_TOT) ? yg[(size_t)bp * 192 + c] : 0.f;
    }
    __syncthreads();

    int g = t / 48, cp = t % 48;
    if (g >= 5) return;
    float acc0[8], acc1[8];
    #pragma unroll
    for (int i = 0; i < 8; ++i) { acc0[i] = 0.f; acc1[i] = 0.f; }
    #pragma unroll 2
    for (int k = 0; k < 192; ++k) {
        float4 a = *(const float4*)&xl[k * 44 + g * 8];
        float4 b = *(const float4*)&xl[k * 44 + g * 8 + 4];
        float xv[8] = {a.x, a.y, a.z, a.w, b.x, b.y, b.z, b.w};
        float2 w = *(const float2*)&WoT[k * 96 + 2 * cp];
        #pragma unroll
        for (int i = 0; i < 8; ++i) {
            acc0[i] += w.x * xv[i];
            acc1[i] += w.y * xv[i];
        }
    }
    #pragma unroll
    for (int i = 0; i < 8; ++i) {
        int bp = p0 + g * 8 + i;
        if (bp < BP_TOT) {
            out[(size_t)bp * 96 + 2 * cp]     = acc0[i];
            out[(size_t)bp * 96 + 2 * cp + 1] = acc1[i];
        }
    }
}

// ---------------------------------------------------------------------------
extern "C" void kernel_launch(void* const* d_in, const int* in_sizes, int n_in,
                              void* d_out, int out_size, void* d_ws, size_t ws_size,
                              hipStream_t stream)
{
    const float* x    = (const float*)d_in[0];
    const float* Wp   = (const float*)d_in[1];
    const float* cw   = (const float*)d_in[2];
    const float* cb   = (const float*)d_in[3];
    const float* xpw  = (const float*)d_in[4];
    const float* dtw  = (const float*)d_in[5];
    const float* dtb  = (const float*)d_in[6];
    const float* Alog = (const float*)d_in[7];
    const float* Ds   = (const float*)d_in[8];
    const float* onw  = (const float*)d_in[9];
    const float* onb  = (const float*)d_in[10];
    const float* Wo   = (const float*)d_in[11];
    float* out = (float*)d_out;

    const size_t NBP  = (size_t)BP_TOT * 192;        // 1,572,864 floats
    const size_t NXD  = (size_t)BP_TOT * 152;        // 1,245,184 floats
    const size_t NSC  = (size_t)BB * 4 * SCH * 3072; // 3,145,728 floats
    const size_t NCD  = (size_t)BB * 4 * SCH * TCH * 192; // 6,291,456 floats
    float* WS    = (float*)d_ws;
    float* xc    = WS;                  // conv output (b,p,d)
    float* zb    = WS + NBP;            // gate z
    float* xiy   = WS + 2 * NBP;        // xi (conv in), later y accumulator
    float* xdbl  = WS + 3 * NBP;        // (b,p,152)
    float* hend  = xdbl + NXD;
    float* prodA = hend + NSC;          // after pass2: h_init
    float* cdbuf = prodA + NSC;         // per-step cumulative delta
    float* WpT   = cdbuf + NCD;
    float* XpwT  = WpT + 384 * 96;
    float* WoT   = XpwT + 152 * 192;
    float* yg    = hend;                // reuse hend after pass 3

    k_wtrans <<<144, 256, 0, stream>>>(Wp, xpw, Wo, WpT, XpwT, WoT);
    k_inproj <<<1024, 192, 0, stream>>>(x, WpT, xiy, zb);
    k_conv   <<<6144, 256, 0, stream>>>(xiy, cw, cb, xc);
    hipMemsetAsync(xiy, 0, NBP * sizeof(float), stream);  // y accumulator
    k_xdbl   <<<171, 256, 0, stream>>>(xc, XpwT, xdbl);
    k_scan1  <<<1024, 192, 0, stream>>>(xc, xdbl, dtw, dtb, Alog, Ds, hend, prodA, cdbuf, xiy);
    k_scan2  <<<96, 256, 0, stream>>>(hend, prodA);
    k_scan3  <<<1024, 192, 0, stream>>>(xc, xdbl, dtw, dtb, Alog, Ds, prodA, cdbuf, xiy);
    k_lngate <<<8192, 192, 0, stream>>>(xiy, zb, onw, onb, yg);
    k_outproj<<<205, 256, 0, stream>>>(yg, WoT, out);
}

// Round 4
// 231.236 us; speedup vs baseline: 1.1725x; 1.1725x over previous
//
#include <hip/hip_runtime.h>
#include <math.h>

// Problem constants
#define DMODEL 96
#define DIN    192
#define NST    16
#define RK     6
#define KDIR   4
#define LLEN   4096   // H*W
#define BB     2
#define BP_TOT 8192   // B*L
#define SCH    128    // scan chunks
#define TCH    32     // steps per chunk (L/SCH)

// ---------------------------------------------------------------------------
// K1: in_proj. 1024 blocks x 192 thr, 8 positions/block.
// Thread t computes output cols t (->xi) and t+192 (->z) for 8 positions.
__global__ __launch_bounds__(192) void k_inproj(const float* __restrict__ x,
                                                const float* __restrict__ Wp,
                                                float* __restrict__ xi,
                                                float* __restrict__ z)
{
    __shared__ float xs[8 * 96];
    const int t  = threadIdx.x;
    const int p0 = blockIdx.x * 8;
    #pragma unroll
    for (int idx = t; idx < 768; idx += 192)
        xs[idx] = x[(size_t)p0 * 96 + idx];   // 8 positions contiguous
    __syncthreads();

    float acc0[8], acc1[8];
    #pragma unroll
    for (int i = 0; i < 8; ++i) { acc0[i] = 0.f; acc1[i] = 0.f; }
    const float* w0p = Wp + (size_t)t * 96;
    const float* w1p = Wp + (size_t)(t + 192) * 96;
    for (int k = 0; k < 96; k += 4) {
        float4 w0 = *(const float4*)(w0p + k);
        float4 w1 = *(const float4*)(w1p + k);
        #pragma unroll
        for (int p = 0; p < 8; ++p) {
            float4 xv = *(const float4*)&xs[p * 96 + k];
            acc0[p] = fmaf(w0.x, xv.x, fmaf(w0.y, xv.y, fmaf(w0.z, xv.z, fmaf(w0.w, xv.w, acc0[p]))));
            acc1[p] = fmaf(w1.x, xv.x, fmaf(w1.y, xv.y, fmaf(w1.z, xv.z, fmaf(w1.w, xv.w, acc1[p]))));
        }
    }
    #pragma unroll
    for (int p = 0; p < 8; ++p) {
        xi[(size_t)(p0 + p) * 192 + t] = acc0[p];
        z [(size_t)(p0 + p) * 192 + t] = acc1[p];
    }
}

// ---------------------------------------------------------------------------
// K2: depthwise 3x3 conv (SAME) + bias + SiLU.  (b,p,d) layout, coalesced in d.
__global__ __launch_bounds__(256) void k_conv(const float* __restrict__ xi,
                                              const float* __restrict__ cw,
                                              const float* __restrict__ cb,
                                              float* __restrict__ xc)
{
    int tid = blockIdx.x * 256 + threadIdx.x;  // BP_TOT*192 total
    int d  = tid % 192;
    int bp = tid / 192;
    int p  = bp & 4095;
    int b  = bp >> 12;
    int h  = p >> 6, w = p & 63;
    float s = cb[d];
    #pragma unroll
    for (int ky = 0; ky < 3; ++ky) {
        int hh = h + ky - 1;
        if (hh < 0 || hh >= 64) continue;
        #pragma unroll
        for (int kx = 0; kx < 3; ++kx) {
            int ww = w + kx - 1;
            if (ww < 0 || ww >= 64) continue;
            s += xi[((size_t)b * 4096 + hh * 64 + ww) * 192 + d] * cw[d * 9 + ky * 3 + kx];
        }
    }
    xc[tid] = s * (1.f / (1.f + __expf(-s)));  // SiLU
}

// ---------------------------------------------------------------------------
// inverse scan permutation: position p (0..4095) -> scan index l for dir kd
__device__ __forceinline__ int inv_perm(int kd, int p)
{
    if (kd == 0) return p;
    if (kd == 1) return ((p & 63) << 6) | (p >> 6);
    if (kd == 2) return 4095 - p;
    return 4095 - (((p & 63) << 6) | (p >> 6));
}

// scan-order -> position permutation
__device__ __forceinline__ int perm_pos(int k, int l)
{
    if (k == 0) return l;
    if (k == 1) return ((l & 63) << 6) | (l >> 6);
    if (k == 2) return 4095 - l;
    int lr = 4095 - l;
    return ((lr & 63) << 6) | (lr >> 6);
}

// ---------------------------------------------------------------------------
// K3: x_proj, 1024 blocks x 192 thr, 8 positions/block, col = t (t<152).
// Output written in per-direction SCAN ORDER: xdk[(b*4+kd)][l][38].
__global__ __launch_bounds__(192) void k_xdbl(const float* __restrict__ xc,
                                              const float* __restrict__ xpw,
                                              float* __restrict__ xdk)
{
    __shared__ float xs[8 * 192];
    const int t  = threadIdx.x;
    const int p0 = blockIdx.x * 8;
    #pragma unroll
    for (int idx = t; idx < 1536; idx += 192)
        xs[idx] = xc[(size_t)p0 * 192 + idx];
    __syncthreads();
    if (t >= 152) return;

    const int kd = t / 38, r = t % 38;
    float acc[8];
    #pragma unroll
    for (int i = 0; i < 8; ++i) acc[i] = 0.f;
    const float* wr = xpw + (size_t)t * 192;
    for (int k = 0; k < 192; k += 4) {
        float4 w = *(const float4*)(wr + k);
        #pragma unroll
        for (int p = 0; p < 8; ++p) {
            float4 xv = *(const float4*)&xs[p * 192 + k];
            acc[p] = fmaf(w.x, xv.x, fmaf(w.y, xv.y, fmaf(w.z, xv.z, fmaf(w.w, xv.w, acc[p]))));
        }
    }
    #pragma unroll
    for (int p = 0; p < 8; ++p) {
        int bp = p0 + p;
        int b  = bp >> 12, pp = bp & 4095;
        int l  = inv_perm(kd, pp);
        xdk[((size_t)(b * 4 + kd) * 4096 + l) * 38 + r] = acc[p];
    }
}

__device__ __forceinline__ float softplus_fast(float x)
{
    float r = __logf(1.f + __expf(x));
    return (x > 15.f) ? x : r;
}

// binary power chain: aa[n] = e1^(n+1), depth 4
__device__ __forceinline__ void pow_chain(float e1, float* aa)
{
    float e2 = e1 * e1, e4 = e2 * e2, e8 = e4 * e4, e16 = e8 * e8;
    float e3 = e2 * e1, e5 = e4 * e1, e6 = e4 * e2, e7 = e4 * e3;
    aa[0] = e1;  aa[1] = e2;  aa[2] = e3;  aa[3] = e4;
    aa[4] = e5;  aa[5] = e6;  aa[6] = e7;  aa[7] = e8;
    aa[8] = e8 * e1;  aa[9] = e8 * e2;  aa[10] = e8 * e3;  aa[11] = e8 * e4;
    aa[12] = e8 * e5; aa[13] = e8 * e6; aa[14] = e8 * e7;  aa[15] = e16;
}

// LDS layout per step (stride 40, 16B-aligned rows): B[0..15], C[16..31], dt[32..37]
__device__ __forceinline__ int sm_remap(int c)  // c: 0..5 dt, 6..21 B, 22..37 C
{
    return (c < 6) ? (32 + c) : (c - 6);
}

// ---------------------------------------------------------------------------
// K4: scan pass 1 — per-chunk local recurrence from h=0; store h_end, prodA.
// prodA[n] = exp(A[n]*sum_delta). Staging from xdk is fully coalesced.
__global__ __launch_bounds__(192) void k_scan1(const float* __restrict__ xc,
                                               const float* __restrict__ xdk,
                                               const float* __restrict__ dtw,
                                               const float* __restrict__ dtb,
                                               const float* __restrict__ Alog,
                                               float* __restrict__ hend,
                                               float* __restrict__ prodA)
{
    __shared__ float sm[TCH * 40];
    const int t   = threadIdx.x;
    const int blk = blockIdx.x;
    const int s = blk & (SCH - 1), k = (blk >> 7) & 3, b = blk >> 9;
    const int kd = k * 192 + t;
    const int l0 = s * TCH;

    const float* src = xdk + ((size_t)(b * 4 + k) * 4096 + l0) * 38;
    #pragma unroll
    for (int idx = t; idx < TCH * 38; idx += 192) {
        int st = idx / 38, c = idx % 38;
        sm[st * 40 + sm_remap(c)] = src[idx];
    }

    const float A0 = -__expf(Alog[kd * 16]);
    bool fast = true;
    #pragma unroll
    for (int n = 1; n < 16; ++n) {
        float An = -__expf(Alog[kd * 16 + n]);
        fast = fast && (fabsf(An - (float)(n + 1) * A0) <= 1e-3f * fabsf(An));
    }
    float wdt[6];
    #pragma unroll
    for (int r = 0; r < 6; ++r) wdt[r] = dtw[kd * 6 + r];
    const float bias = dtb[kd];

    float h[16];
    #pragma unroll
    for (int n = 0; n < 16; ++n) h[n] = 0.f;
    float cd = 0.f;

    const float* xcb = xc + (size_t)b * 4096 * 192;
    int allfast = __syncthreads_and((int)fast);

    int p_cur = perm_pos(k, l0);
    float u = xcb[(size_t)p_cur * 192 + t];

    if (allfast) {
        for (int st = 0; st < TCH; ++st) {
            int p_next = (st + 1 < TCH) ? perm_pos(k, l0 + st + 1) : p_cur;
            float u_next = xcb[(size_t)p_next * 192 + t];
            const float* r = &sm[st * 40];
            float4 dq = *(const float4*)(r + 32);
            float xv = bias + dq.x * wdt[0] + dq.y * wdt[1] + dq.z * wdt[2]
                            + dq.w * wdt[3] + r[36] * wdt[4] + r[37] * wdt[5];
            float delta = softplus_fast(xv);
            cd += delta;
            float du = delta * u;
            float aa[16];
            pow_chain(__expf(delta * A0), aa);
            float4 b0 = *(const float4*)(r),      b1 = *(const float4*)(r + 4);
            float4 b2 = *(const float4*)(r + 8),  b3 = *(const float4*)(r + 12);
            float bv[16] = {b0.x, b0.y, b0.z, b0.w, b1.x, b1.y, b1.z, b1.w,
                            b2.x, b2.y, b2.z, b2.w, b3.x, b3.y, b3.z, b3.w};
            #pragma unroll
            for (int n = 0; n < 16; ++n) h[n] = fmaf(h[n], aa[n], du * bv[n]);
            u = u_next; p_cur = p_next;
        }
    } else {
        for (int st = 0; st < TCH; ++st) {
            int p_next = (st + 1 < TCH) ? perm_pos(k, l0 + st + 1) : p_cur;
            float u_next = xcb[(size_t)p_next * 192 + t];
            const float* r = &sm[st * 40];
            float xv = bias;
            #pragma unroll
            for (int j = 0; j < 6; ++j) xv += r[32 + j] * wdt[j];
            float delta = softplus_fast(xv);
            cd += delta;
            float du = delta * u;
            #pragma unroll
            for (int n = 0; n < 16; ++n) {
                float An = -__expf(Alog[kd * 16 + n]);
                h[n] = fmaf(h[n], __expf(delta * An), du * r[n]);
            }
            u = u_next; p_cur = p_next;
        }
    }

    size_t base = (size_t)blk * 3072 + t * 16;
    float ap[16];
    if (allfast) {
        pow_chain(__expf(cd * A0), ap);
    } else {
        #pragma unroll
        for (int n = 0; n < 16; ++n)
            ap[n] = __expf(-__expf(Alog[kd * 16 + n]) * cd);
    }
    #pragma unroll
    for (int i = 0; i < 4; ++i) {
        *(float4*)&hend [base + 4 * i] = make_float4(h[4*i], h[4*i+1], h[4*i+2], h[4*i+3]);
        *(float4*)&prodA[base + 4 * i] = make_float4(ap[4*i], ap[4*i+1], ap[4*i+2], ap[4*i+3]);
    }
}

// ---------------------------------------------------------------------------
// K5: scan pass 2 — serial composition over chunks; prodA becomes h_init.
__global__ __launch_bounds__(256) void k_scan2(const float* __restrict__ hend,
                                               float* __restrict__ prodA)
{
    int tid = blockIdx.x * 256 + threadIdx.x;  // 24576 lanes
    int n  = tid & 15;
    int d  = (tid >> 4) % 192;
    int bk = tid / (192 * 16);
    size_t base = (size_t)bk * SCH * 3072 + d * 16 + n;
    float carry = 0.f;
    for (int s = 0; s < SCH; ++s) {
        size_t a = base + (size_t)s * 3072;
        float pa = prodA[a];
        float he = hend[a];
        prodA[a] = carry;            // becomes h_init
        carry = fmaf(pa, carry, he);
    }
}

// ---------------------------------------------------------------------------
// K6: scan pass 3 — replay from h_init, emit y (+D*u), atomic-merge directions.
__global__ __launch_bounds__(192) void k_scan3(const float* __restrict__ xc,
                                               const float* __restrict__ xdk,
                                               const float* __restrict__ dtw,
                                               const float* __restrict__ dtb,
                                               const float* __restrict__ Alog,
                                               const float* __restrict__ Ds,
                                               const float* __restrict__ hinit,
                                               float* __restrict__ y)
{
    __shared__ float sm[TCH * 40];
    const int t   = threadIdx.x;
    const int blk = blockIdx.x;
    const int s = blk & (SCH - 1), k = (blk >> 7) & 3, b = blk >> 9;
    const int kd = k * 192 + t;
    const int l0 = s * TCH;

    const float* src = xdk + ((size_t)(b * 4 + k) * 4096 + l0) * 38;
    #pragma unroll
    for (int idx = t; idx < TCH * 38; idx += 192) {
        int st = idx / 38, c = idx % 38;
        sm[st * 40 + sm_remap(c)] = src[idx];
    }

    const float A0 = -__expf(Alog[kd * 16]);
    bool fast = true;
    #pragma unroll
    for (int n = 1; n < 16; ++n) {
        float An = -__expf(Alog[kd * 16 + n]);
        fast = fast && (fabsf(An - (float)(n + 1) * A0) <= 1e-3f * fabsf(An));
    }
    float wdt[6];
    #pragma unroll
    for (int r = 0; r < 6; ++r) wdt[r] = dtw[kd * 6 + r];
    const float bias = dtb[kd];
    const float Dk   = Ds[kd];

    float h[16];
    size_t hbase = (size_t)blk * 3072 + t * 16;
    #pragma unroll
    for (int i = 0; i < 4; ++i) {
        float4 v = *(const float4*)&hinit[hbase + 4 * i];
        h[4*i] = v.x; h[4*i+1] = v.y; h[4*i+2] = v.z; h[4*i+3] = v.w;
    }

    const float* xcb = xc + (size_t)b * 4096 * 192;
    float* yb = y + (size_t)b * 4096 * 192;
    int allfast = __syncthreads_and((int)fast);

    int p_cur = perm_pos(k, l0);
    float u = xcb[(size_t)p_cur * 192 + t];

    if (allfast) {
        for (int st = 0; st < TCH; ++st) {
            int p_next = (st + 1 < TCH) ? perm_pos(k, l0 + st + 1) : p_cur;
            float u_next = xcb[(size_t)p_next * 192 + t];
            const float* r = &sm[st * 40];
            float4 dq = *(const float4*)(r + 32);
            float xv = bias + dq.x * wdt[0] + dq.y * wdt[1] + dq.z * wdt[2]
                            + dq.w * wdt[3] + r[36] * wdt[4] + r[37] * wdt[5];
            float delta = softplus_fast(xv);
            float du = delta * u;
            float aa[16];
            pow_chain(__expf(delta * A0), aa);
            float4 b0 = *(const float4*)(r),      b1 = *(const float4*)(r + 4);
            float4 b2 = *(const float4*)(r + 8),  b3 = *(const float4*)(r + 12);
            float4 c0 = *(const float4*)(r + 16), c1 = *(const float4*)(r + 20);
            float4 c2 = *(const float4*)(r + 24), c3 = *(const float4*)(r + 28);
            float bv[16] = {b0.x, b0.y, b0.z, b0.w, b1.x, b1.y, b1.z, b1.w,
                            b2.x, b2.y, b2.z, b2.w, b3.x, b3.y, b3.z, b3.w};
            float cv[16] = {c0.x, c0.y, c0.z, c0.w, c1.x, c1.y, c1.z, c1.w,
                            c2.x, c2.y, c2.z, c2.w, c3.x, c3.y, c3.z, c3.w};
            float acc = Dk * u;
            #pragma unroll
            for (int n = 0; n < 16; ++n) {
                h[n] = fmaf(h[n], aa[n], du * bv[n]);
                acc  = fmaf(h[n], cv[n], acc);
            }
            unsafeAtomicAdd(&yb[(size_t)p_cur * 192 + t], acc);
            u = u_next; p_cur = p_next;
        }
    } else {
        for (int st = 0; st < TCH; ++st) {
            int p_next = (st + 1 < TCH) ? perm_pos(k, l0 + st + 1) : p_cur;
            float u_next = xcb[(size_t)p_next * 192 + t];
            const float* r = &sm[st * 40];
            float xv = bias;
            #pragma unroll
            for (int j = 0; j < 6; ++j) xv += r[32 + j] * wdt[j];
            float delta = softplus_fast(xv);
            float du = delta * u;
            float acc = Dk * u;
            #pragma unroll
            for (int n = 0; n < 16; ++n) {
                float An = -__expf(Alog[kd * 16 + n]);
                h[n] = fmaf(h[n], __expf(delta * An), du * r[n]);
                acc  = fmaf(h[n], r[16 + n], acc);
            }
            unsafeAtomicAdd(&yb[(size_t)p_cur * 192 + t], acc);
            u = u_next; p_cur = p_next;
        }
    }
}

// ---------------------------------------------------------------------------
// K7: LayerNorm(192) + out_norm affine + SiLU(z) gate
__global__ __launch_bounds__(192) void k_lngate(const float* __restrict__ y,
                                                const float* __restrict__ z,
                                                const float* __restrict__ onw,
                                                const float* __restrict__ onb,
                                                float* __restrict__ yg)
{
    const int t  = threadIdx.x;
    const int bp = blockIdx.x;
    float yv = y[(size_t)bp * 192 + t];
    float s1 = yv, s2 = yv * yv;
    #pragma unroll
    for (int off = 32; off; off >>= 1) {
        s1 += __shfl_xor(s1, off, 64);
        s2 += __shfl_xor(s2, off, 64);
    }
    __shared__ float rs[3], rq[3];
    int wv = t >> 6;
    if ((t & 63) == 0) { rs[wv] = s1; rq[wv] = s2; }
    __syncthreads();
    float tot  = rs[0] + rs[1] + rs[2];
    float totq = rq[0] + rq[1] + rq[2];
    float mean = tot * (1.f / 192.f);
    float var  = totq * (1.f / 192.f) - mean * mean;
    float rinv = rsqrtf(var + 1e-5f);
    float yn = (yv - mean) * rinv * onw[t] + onb[t];
    float zv = z[(size_t)bp * 192 + t];
    float sig = 1.f / (1.f + __expf(-zv));
    yg[(size_t)bp * 192 + t] = yn * (zv * sig);
}

// ---------------------------------------------------------------------------
// K8: out_proj. 1024 blocks x 192 thr, 8 pos/block; thread (pg=t/96, c=t%96)
// computes col c for 4 positions. Wo rows are already [c][k].
__global__ __launch_bounds__(192) void k_outproj(const float* __restrict__ yg,
                                                 const float* __restrict__ Wo,
                                                 float* __restrict__ out)
{
    __shared__ float ys[8 * 192];
    const int t  = threadIdx.x;
    const int p0 = blockIdx.x * 8;
    #pragma unroll
    for (int idx = t; idx < 1536; idx += 192)
        ys[idx] = yg[(size_t)p0 * 192 + idx];
    __syncthreads();

    const int pg = t / 96, c = t % 96;
    float acc[4];
    #pragma unroll
    for (int i = 0; i < 4; ++i) acc[i] = 0.f;
    const float* wr = Wo + (size_t)c * 192;
    for (int k = 0; k < 192; k += 4) {
        float4 w = *(const float4*)(wr + k);
        #pragma unroll
        for (int i = 0; i < 4; ++i) {
            float4 xv = *(const float4*)&ys[(pg * 4 + i) * 192 + k];
            acc[i] = fmaf(w.x, xv.x, fmaf(w.y, xv.y, fmaf(w.z, xv.z, fmaf(w.w, xv.w, acc[i]))));
        }
    }
    #pragma unroll
    for (int i = 0; i < 4; ++i)
        out[(size_t)(p0 + pg * 4 + i) * 96 + c] = acc[i];
}

// ---------------------------------------------------------------------------
extern "C" void kernel_launch(void* const* d_in, const int* in_sizes, int n_in,
                              void* d_out, int out_size, void* d_ws, size_t ws_size,
                              hipStream_t stream)
{
    const float* x    = (const float*)d_in[0];
    const float* Wp   = (const float*)d_in[1];
    const float* cw   = (const float*)d_in[2];
    const float* cb   = (const float*)d_in[3];
    const float* xpw  = (const float*)d_in[4];
    const float* dtw  = (const float*)d_in[5];
    const float* dtb  = (const float*)d_in[6];
    const float* Alog = (const float*)d_in[7];
    const float* Ds   = (const float*)d_in[8];
    const float* onw  = (const float*)d_in[9];
    const float* onb  = (const float*)d_in[10];
    const float* Wo   = (const float*)d_in[11];
    float* out = (float*)d_out;

    const size_t NBP  = (size_t)BP_TOT * 192;        // 1,572,864 floats
    const size_t NXD  = (size_t)BB * 4 * 4096 * 38;  // 1,245,184 floats
    const size_t NSC  = (size_t)BB * 4 * SCH * 3072; // 3,145,728 floats
    float* WS    = (float*)d_ws;
    float* xc    = WS;                  // conv output (b,p,d)
    float* zb    = WS + NBP;            // gate z
    float* xiy   = WS + 2 * NBP;        // xi (conv in), later y accumulator
    float* xdk   = WS + 3 * NBP;        // (b,k,l,38) scan-ordered x_dbl
    float* hend  = xdk + NXD;
    float* prodA = hend + NSC;          // after pass2: h_init
    float* yg    = hend;                // reuse hend after scan2

    k_inproj <<<1024, 192, 0, stream>>>(x, Wp, xiy, zb);
    k_conv   <<<6144, 256, 0, stream>>>(xiy, cw, cb, xc);
    hipMemsetAsync(xiy, 0, NBP * sizeof(float), stream);  // y accumulator
    k_xdbl   <<<1024, 192, 0, stream>>>(xc, xpw, xdk);
    k_scan1  <<<1024, 192, 0, stream>>>(xc, xdk, dtw, dtb, Alog, hend, prodA);
    k_scan2  <<<96, 256, 0, stream>>>(hend, prodA);
    k_scan3  <<<1024, 192, 0, stream>>>(xc, xdk, dtw, dtb, Alog, Ds, prodA, xiy);
    k_lngate <<<8192, 192, 0, stream>>>(xiy, zb, onw, onb, yg);
    k_outproj<<<1024, 192, 0, stream>>>(yg, Wo, out);
}

// Round 6
// 229.344 us; speedup vs baseline: 1.1822x; 1.0082x over previous
//
#include <hip/hip_runtime.h>
#include <math.h>

// Problem constants
#define DMODEL 96
#define DIN    192
#define NST    16
#define RK     6
#define KDIR   4
#define LLEN   4096   // H*W
#define BB     2
#define BP_TOT 8192   // B*L
#define SCH    128    // scan chunks per (b,k)
#define TCH    32     // steps per chunk (L/SCH)

// ---------------------------------------------------------------------------
// K1: in_proj. 1024 blocks x 192 thr, 8 positions/block.
__global__ __launch_bounds__(192) void k_inproj(const float* __restrict__ x,
                                                const float* __restrict__ Wp,
                                                float* __restrict__ xi,
                                                float* __restrict__ z)
{
    __shared__ float xs[8 * 96];
    const int t  = threadIdx.x;
    const int p0 = blockIdx.x * 8;
    for (int idx = t; idx < 768; idx += 192)
        xs[idx] = x[(size_t)p0 * 96 + idx];
    __syncthreads();

    float acc0[8], acc1[8];
    #pragma unroll
    for (int i = 0; i < 8; ++i) { acc0[i] = 0.f; acc1[i] = 0.f; }
    const float* w0p = Wp + (size_t)t * 96;
    const float* w1p = Wp + (size_t)(t + 192) * 96;
    for (int k = 0; k < 96; k += 4) {
        float4 w0 = *(const float4*)(w0p + k);
        float4 w1 = *(const float4*)(w1p + k);
        #pragma unroll
        for (int p = 0; p < 8; ++p) {
            float4 xv = *(const float4*)&xs[p * 96 + k];
            acc0[p] = fmaf(w0.x, xv.x, fmaf(w0.y, xv.y, fmaf(w0.z, xv.z, fmaf(w0.w, xv.w, acc0[p]))));
            acc1[p] = fmaf(w1.x, xv.x, fmaf(w1.y, xv.y, fmaf(w1.z, xv.z, fmaf(w1.w, xv.w, acc1[p]))));
        }
    }
    #pragma unroll
    for (int p = 0; p < 8; ++p) {
        xi[(size_t)(p0 + p) * 192 + t] = acc0[p];
        z [(size_t)(p0 + p) * 192 + t] = acc1[p];
    }
}

// ---------------------------------------------------------------------------
// K2: depthwise 3x3 conv (SAME) + bias + SiLU.
__global__ __launch_bounds__(256) void k_conv(const float* __restrict__ xi,
                                              const float* __restrict__ cw,
                                              const float* __restrict__ cb,
                                              float* __restrict__ xc)
{
    int tid = blockIdx.x * 256 + threadIdx.x;
    int d  = tid % 192;
    int bp = tid / 192;
    int p  = bp & 4095;
    int b  = bp >> 12;
    int h  = p >> 6, w = p & 63;
    float s = cb[d];
    #pragma unroll
    for (int ky = 0; ky < 3; ++ky) {
        int hh = h + ky - 1;
        if (hh < 0 || hh >= 64) continue;
        #pragma unroll
        for (int kx = 0; kx < 3; ++kx) {
            int ww = w + kx - 1;
            if (ww < 0 || ww >= 64) continue;
            s += xi[((size_t)b * 4096 + hh * 64 + ww) * 192 + d] * cw[d * 9 + ky * 3 + kx];
        }
    }
    xc[tid] = s * (1.f / (1.f + __expf(-s)));
}

// ---------------------------------------------------------------------------
__device__ __forceinline__ int inv_perm(int kd, int p)
{
    if (kd == 0) return p;
    if (kd == 1) return ((p & 63) << 6) | (p >> 6);
    if (kd == 2) return 4095 - p;
    return 4095 - (((p & 63) << 6) | (p >> 6));
}

__device__ __forceinline__ int perm_pos(int k, int l)
{
    if (k == 0) return l;
    if (k == 1) return ((l & 63) << 6) | (l >> 6);
    if (k == 2) return 4095 - l;
    int lr = 4095 - l;
    return ((lr & 63) << 6) | (lr >> 6);
}

__device__ __forceinline__ float softplus_fast(float x)
{
    float r = __logf(1.f + __expf(x));
    return (x > 15.f) ? x : r;
}

// binary power chain: aa[n] = e1^(n+1)
__device__ __forceinline__ void pow_chain(float e1, float* aa)
{
    float e2 = e1 * e1, e4 = e2 * e2, e8 = e4 * e4, e16 = e8 * e8;
    float e3 = e2 * e1, e5 = e4 * e1, e6 = e4 * e2, e7 = e4 * e3;
    aa[0] = e1;  aa[1] = e2;  aa[2] = e3;  aa[3] = e4;
    aa[4] = e5;  aa[5] = e6;  aa[6] = e7;  aa[7] = e8;
    aa[8] = e8 * e1;  aa[9] = e8 * e2;  aa[10] = e8 * e3;  aa[11] = e8 * e4;
    aa[12] = e8 * e5; aa[13] = e8 * e6; aa[14] = e8 * e7;  aa[15] = e16;
}

// LDS per step (stride 40): B[0..15], C[16..31], dt[32..37]
__device__ __forceinline__ int sm_remap(int c)  // src col c: 0..5 dt, 6..21 B, 22..37 C
{
    return (c < 6) ? (32 + c) : (c - 6);
}

// ---------------------------------------------------------------------------
// K3: x_proj (scan-ordered out) + zero the y accumulator.
__global__ __launch_bounds__(192) void k_xdbl(const float* __restrict__ xc,
                                              const float* __restrict__ xpw,
                                              float* __restrict__ xdk,
                                              float* __restrict__ y)
{
    __shared__ float xs[8 * 192];
    const int t  = threadIdx.x;
    const int p0 = blockIdx.x * 8;
    for (int idx = t; idx < 1536; idx += 192) {
        xs[idx] = xc[(size_t)p0 * 192 + idx];
        y[(size_t)p0 * 192 + idx] = 0.f;
    }
    __syncthreads();
    if (t >= 152) return;

    const int kd = t / 38, r = t % 38;
    float acc[8];
    #pragma unroll
    for (int i = 0; i < 8; ++i) acc[i] = 0.f;
    const float* wr = xpw + (size_t)t * 192;
    for (int k = 0; k < 192; k += 4) {
        float4 w = *(const float4*)(wr + k);
        #pragma unroll
        for (int p = 0; p < 8; ++p) {
            float4 xv = *(const float4*)&xs[p * 192 + k];
            acc[p] = fmaf(w.x, xv.x, fmaf(w.y, xv.y, fmaf(w.z, xv.z, fmaf(w.w, xv.w, acc[p]))));
        }
    }
    #pragma unroll
    for (int p = 0; p < 8; ++p) {
        int bp = p0 + p;
        int b  = bp >> 12, pp = bp & 4095;
        int l  = inv_perm(kd, pp);
        xdk[((size_t)(b * 4 + kd) * 4096 + l) * 38 + r] = acc[p];
    }
}

// ---------------------------------------------------------------------------
// K4: scan pass 1 — local recurrence from h=0. Fast path: emit local y
// (C·h_loc + D·u) via atomics, store per-step cumulative delta. Both paths:
// store h_end and prodA[n]=exp(A[n]*sum_delta).
__global__ __launch_bounds__(192) void k_scan1(const float* __restrict__ xc,
                                               const float* __restrict__ xdk,
                                               const float* __restrict__ dtw,
                                               const float* __restrict__ dtb,
                                               const float* __restrict__ Alog,
                                               const float* __restrict__ Ds,
                                               float* __restrict__ hend,
                                               float* __restrict__ prodA,
                                               float* __restrict__ cdbuf,
                                               float* __restrict__ y)
{
    __shared__ float sm[TCH * 40];
    const int t   = threadIdx.x;
    const int blk = blockIdx.x;
    const int s = blk & (SCH - 1), k = (blk >> 7) & 3, b = blk >> 9;
    const int kd = k * 192 + t;
    const int l0 = s * TCH;

    const float* src = xdk + ((size_t)(b * 4 + k) * 4096 + l0) * 38;
    for (int idx = t; idx < TCH * 38; idx += 192) {
        int st = idx / 38, c = idx % 38;
        sm[st * 40 + sm_remap(c)] = src[idx];
    }

    const float A0 = -__expf(Alog[kd * 16]);
    bool fast = true;
    #pragma unroll
    for (int n = 1; n < 16; ++n) {
        float An = -__expf(Alog[kd * 16 + n]);
        fast = fast && (fabsf(An - (float)(n + 1) * A0) <= 1e-3f * fabsf(An));
    }
    float wdt[6];
    #pragma unroll
    for (int r = 0; r < 6; ++r) wdt[r] = dtw[kd * 6 + r];
    const float bias = dtb[kd];
    const float Dk   = Ds[kd];

    float h[16];
    #pragma unroll
    for (int n = 0; n < 16; ++n) h[n] = 0.f;
    float cd = 0.f;

    const float* xcb = xc + (size_t)b * 4096 * 192;
    float* yb = y + (size_t)b * 4096 * 192;
    int allfast = __syncthreads_and((int)fast);

    int p_cur = perm_pos(k, l0);
    float u = xcb[(size_t)p_cur * 192 + t];

    if (allfast) {
        for (int st = 0; st < TCH; ++st) {
            int p_next = (st + 1 < TCH) ? perm_pos(k, l0 + st + 1) : p_cur;
            float u_next = xcb[(size_t)p_next * 192 + t];
            const float* r = &sm[st * 40];
            float4 dq = *(const float4*)(r + 32);
            float xv = bias + dq.x * wdt[0] + dq.y * wdt[1] + dq.z * wdt[2]
                            + dq.w * wdt[3] + r[36] * wdt[4] + r[37] * wdt[5];
            float delta = softplus_fast(xv);
            cd += delta;
            cdbuf[((size_t)blk * TCH + st) * 192 + t] = cd;
            float du = delta * u;
            float aa[16];
            pow_chain(__expf(delta * A0), aa);
            float4 b0 = *(const float4*)(r),      b1 = *(const float4*)(r + 4);
            float4 b2 = *(const float4*)(r + 8),  b3 = *(const float4*)(r + 12);
            float4 c0 = *(const float4*)(r + 16), c1 = *(const float4*)(r + 20);
            float4 c2 = *(const float4*)(r + 24), c3 = *(const float4*)(r + 28);
            float bv[16] = {b0.x, b0.y, b0.z, b0.w, b1.x, b1.y, b1.z, b1.w,
                            b2.x, b2.y, b2.z, b2.w, b3.x, b3.y, b3.z, b3.w};
            float cv[16] = {c0.x, c0.y, c0.z, c0.w, c1.x, c1.y, c1.z, c1.w,
                            c2.x, c2.y, c2.z, c2.w, c3.x, c3.y, c3.z, c3.w};
            float acc = Dk * u;
            #pragma unroll
            for (int n = 0; n < 16; ++n) {
                h[n] = fmaf(h[n], aa[n], du * bv[n]);
                acc  = fmaf(h[n], cv[n], acc);
            }
            unsafeAtomicAdd(&yb[(size_t)p_cur * 192 + t], acc);
            u = u_next; p_cur = p_next;
        }
    } else {
        for (int st = 0; st < TCH; ++st) {
            int p_next = (st + 1 < TCH) ? perm_pos(k, l0 + st + 1) : p_cur;
            float u_next = xcb[(size_t)p_next * 192 + t];
            const float* r = &sm[st * 40];
            float xv = bias;
            #pragma unroll
            for (int j = 0; j < 6; ++j) xv += r[32 + j] * wdt[j];
            float delta = softplus_fast(xv);
            cd += delta;
            float du = delta * u;
            #pragma unroll
            for (int n = 0; n < 16; ++n) {
                float An = -__expf(Alog[kd * 16 + n]);
                h[n] = fmaf(h[n], __expf(delta * An), du * r[n]);
            }
            u = u_next; p_cur = p_next;
        }
    }

    size_t base = (size_t)blk * 3072 + t * 16;
    float ap[16];
    if (allfast) {
        pow_chain(__expf(cd * A0), ap);
    } else {
        #pragma unroll
        for (int n = 0; n < 16; ++n)
            ap[n] = __expf(-__expf(Alog[kd * 16 + n]) * cd);
    }
    #pragma unroll
    for (int i = 0; i < 4; ++i) {
        *(float4*)&hend [base + 4 * i] = make_float4(h[4*i], h[4*i+1], h[4*i+2], h[4*i+3]);
        *(float4*)&prodA[base + 4 * i] = make_float4(ap[4*i], ap[4*i+1], ap[4*i+2], ap[4*i+3]);
    }
}

// ---------------------------------------------------------------------------
// K5: scan pass 2 — serial composition over chunks; prodA becomes h_init.
__global__ __launch_bounds__(256) void k_scan2(const float* __restrict__ hend,
                                               float* __restrict__ prodA)
{
    int tid = blockIdx.x * 256 + threadIdx.x;  // 24576 lanes
    int n  = tid & 15;
    int d  = (tid >> 4) % 192;
    int bk = tid / (192 * 16);
    size_t base = (size_t)bk * SCH * 3072 + d * 16 + n;
    float carry = 0.f;
    for (int s = 0; s < SCH; ++s) {
        size_t a = base + (size_t)s * 3072;
        float pa = prodA[a];
        float he = hend[a];
        prodA[a] = carry;            // becomes h_init
        carry = fmaf(pa, carry, he);
    }
}

// ---------------------------------------------------------------------------
// K6: scan pass 3 — fast: correction only, y += sum_n C[n]*h_init[n]*E^(n+1),
// E = exp(cd*A0). Slow: full replay from h_init.
__global__ __launch_bounds__(192) void k_scan3(const float* __restrict__ xc,
                                               const float* __restrict__ xdk,
                                               const float* __restrict__ dtw,
                                               const float* __restrict__ dtb,
                                               const float* __restrict__ Alog,
                                               const float* __restrict__ Ds,
                                               const float* __restrict__ hinit,
                                               const float* __restrict__ cdbuf,
                                               float* __restrict__ y)
{
    __shared__ float sm[TCH * 40];
    const int t   = threadIdx.x;
    const int blk = blockIdx.x;
    const int s = blk & (SCH - 1), k = (blk >> 7) & 3, b = blk >> 9;
    const int kd = k * 192 + t;
    const int l0 = s * TCH;

    const float* src = xdk + ((size_t)(b * 4 + k) * 4096 + l0) * 38;
    float* yb = y + (size_t)b * 4096 * 192;

    const float A0 = -__expf(Alog[kd * 16]);
    bool fast = true;
    #pragma unroll
    for (int n = 1; n < 16; ++n) {
        float An = -__expf(Alog[kd * 16 + n]);
        fast = fast && (fabsf(An - (float)(n + 1) * A0) <= 1e-3f * fabsf(An));
    }
    int allfast = __syncthreads_and((int)fast);

    float hi[16];
    size_t hbase = (size_t)blk * 3072 + t * 16;
    #pragma unroll
    for (int i = 0; i < 4; ++i) {
        float4 v = *(const float4*)&hinit[hbase + 4 * i];
        hi[4*i] = v.x; hi[4*i+1] = v.y; hi[4*i+2] = v.z; hi[4*i+3] = v.w;
    }

    if (allfast) {
        if (s == 0) return;          // h_init == 0 -> no correction
        // stage C columns only (16 per step)
        for (int idx = t; idx < TCH * 16; idx += 192) {
            int st = idx >> 4, c = idx & 15;
            sm[st * 16 + c] = src[st * 38 + 22 + c];
        }
        __syncthreads();
        const float* cdp = cdbuf + (size_t)blk * TCH * 192 + t;
        float cd_next = cdp[0];
        for (int st = 0; st < TCH; ++st) {
            float cdv = cd_next;
            if (st + 1 < TCH) cd_next = cdp[(size_t)(st + 1) * 192];
            float aa[16];
            pow_chain(__expf(cdv * A0), aa);
            const float* r = &sm[st * 16];
            float corr = 0.f;
            #pragma unroll
            for (int n = 0; n < 16; ++n)
                corr = fmaf(aa[n] * hi[n], r[n], corr);
            unsafeAtomicAdd(&yb[(size_t)perm_pos(k, l0 + st) * 192 + t], corr);
        }
    } else {
        for (int idx = t; idx < TCH * 38; idx += 192) {
            int st = idx / 38, c = idx % 38;
            sm[st * 40 + sm_remap(c)] = src[idx];
        }
        __syncthreads();
        const float* xcb = xc + (size_t)b * 4096 * 192;
        float wdt[6];
        #pragma unroll
        for (int r = 0; r < 6; ++r) wdt[r] = dtw[kd * 6 + r];
        const float bias = dtb[kd];
        const float Dk   = Ds[kd];
        float h[16];
        #pragma unroll
        for (int n = 0; n < 16; ++n) h[n] = hi[n];
        int p_cur = perm_pos(k, l0);
        float u = xcb[(size_t)p_cur * 192 + t];
        for (int st = 0; st < TCH; ++st) {
            int p_next = (st + 1 < TCH) ? perm_pos(k, l0 + st + 1) : p_cur;
            float u_next = xcb[(size_t)p_next * 192 + t];
            const float* r = &sm[st * 40];
            float xv = bias;
            #pragma unroll
            for (int j = 0; j < 6; ++j) xv += r[32 + j] * wdt[j];
            float delta = softplus_fast(xv);
            float du = delta * u;
            float acc = Dk * u;
            #pragma unroll
            for (int n = 0; n < 16; ++n) {
                float An = -__expf(Alog[kd * 16 + n]);
                h[n] = fmaf(h[n], __expf(delta * An), du * r[n]);
                acc  = fmaf(h[n], r[16 + n], acc);
            }
            unsafeAtomicAdd(&yb[(size_t)p_cur * 192 + t], acc);
            u = u_next; p_cur = p_next;
        }
    }
}

// ---------------------------------------------------------------------------
// K7: fused LayerNorm + SiLU gate + out_proj. 1024 blocks x 192, 8 pos/block.
__global__ __launch_bounds__(192) void k_lnout(const float* __restrict__ y,
                                               const float* __restrict__ zb,
                                               const float* __restrict__ onw,
                                               const float* __restrict__ onb,
                                               const float* __restrict__ Wo,
                                               float* __restrict__ out)
{
    __shared__ float ys[1536];
    __shared__ float ps[192], pq[192];
    __shared__ float mu[8], ri[8];
    const int t  = threadIdx.x;
    const int p0 = blockIdx.x * 8;

    #pragma unroll
    for (int i = 0; i < 8; ++i)
        ys[i * 192 + t] = y[(size_t)p0 * 192 + i * 192 + t];
    __syncthreads();

    {
        int pg = t / 24, j = t % 24;
        float s1 = 0.f, s2 = 0.f;
        #pragma unroll
        for (int m = 0; m < 8; ++m) {
            float v = ys[pg * 192 + j + 24 * m];
            s1 += v; s2 += v * v;
        }
        ps[t] = s1; pq[t] = s2;
    }
    __syncthreads();
    if (t < 8) {
        float s1 = 0.f, s2 = 0.f;
        #pragma unroll
        for (int j = 0; j < 24; ++j) { s1 += ps[t * 24 + j]; s2 += pq[t * 24 + j]; }
        float mean = s1 * (1.f / 192.f);
        float var  = s2 * (1.f / 192.f) - mean * mean;
        mu[t] = mean;
        ri[t] = rsqrtf(var + 1e-5f);
    }
    __syncthreads();

    {
        float w = onw[t], bo = onb[t];
        #pragma unroll
        for (int i = 0; i < 8; ++i) {
            float v  = ys[i * 192 + t];
            float yn = (v - mu[i]) * ri[i] * w + bo;
            float zv = zb[(size_t)(p0 + i) * 192 + t];
            float sg = 1.f / (1.f + __expf(-zv));
            ys[i * 192 + t] = yn * (zv * sg);
        }
    }
    __syncthreads();

    const int pg = t / 96, c = t % 96;
    float acc[4];
    #pragma unroll
    for (int i = 0; i < 4; ++i) acc[i] = 0.f;
    const float* wr = Wo + (size_t)c * 192;
    for (int k = 0; k < 192; k += 4) {
        float4 w = *(const float4*)(wr + k);
        #pragma unroll
        for (int i = 0; i < 4; ++i) {
            float4 xv = *(const float4*)&ys[(pg * 4 + i) * 192 + k];
            acc[i] = fmaf(w.x, xv.x, fmaf(w.y, xv.y, fmaf(w.z, xv.z, fmaf(w.w, xv.w, acc[i]))));
        }
    }
    #pragma unroll
    for (int i = 0; i < 4; ++i)
        out[(size_t)(p0 + pg * 4 + i) * 96 + c] = acc[i];
}

// ---------------------------------------------------------------------------
extern "C" void kernel_launch(void* const* d_in, const int* in_sizes, int n_in,
                              void* d_out, int out_size, void* d_ws, size_t ws_size,
                              hipStream_t stream)
{
    const float* x    = (const float*)d_in[0];
    const float* Wp   = (const float*)d_in[1];
    const float* cw   = (const float*)d_in[2];
    const float* cb   = (const float*)d_in[3];
    const float* xpw  = (const float*)d_in[4];
    const float* dtw  = (const float*)d_in[5];
    const float* dtb  = (const float*)d_in[6];
    const float* Alog = (const float*)d_in[7];
    const float* Ds   = (const float*)d_in[8];
    const float* onw  = (const float*)d_in[9];
    const float* onb  = (const float*)d_in[10];
    const float* Wo   = (const float*)d_in[11];
    float* out = (float*)d_out;

    const size_t NBP  = (size_t)BP_TOT * 192;
    const size_t NXD  = (size_t)BB * 4 * 4096 * 38;
    const size_t NSC  = (size_t)BB * 4 * SCH * 3072;
    float* WS    = (float*)d_ws;
    float* xc    = WS;
    float* zb    = WS + NBP;
    float* xiy   = WS + 2 * NBP;        // xi (conv in), later y accumulator
    float* xdk   = WS + 3 * NBP;
    float* hend  = xdk + NXD;
    float* prodA = hend + NSC;          // after scan2: h_init
    float* cdbuf = prodA + NSC;         // per-step cumulative delta (25 MB)

    k_inproj<<<1024, 192, 0, stream>>>(x, Wp, xiy, zb);
    k_conv  <<<6144, 256, 0, stream>>>(xiy, cw, cb, xc);
    k_xdbl  <<<1024, 192, 0, stream>>>(xc, xpw, xdk, xiy);
    k_scan1 <<<1024, 192, 0, stream>>>(xc, xdk, dtw, dtb, Alog, Ds, hend, prodA, cdbuf, xiy);
    k_scan2 <<<96, 256, 0, stream>>>(hend, prodA);
    k_scan3 <<<1024, 192, 0, stream>>>(xc, xdk, dtw, dtb, Alog, Ds, prodA, cdbuf, xiy);
    k_lnout <<<1024, 192, 0, stream>>>(xiy, zb, onw, onb, Wo, out);
}

// Round 7
// 210.346 us; speedup vs baseline: 1.2890x; 1.0903x over previous
//
#include <hip/hip_runtime.h>
#include <math.h>

// Problem constants
#define DMODEL 96
#define DIN    192
#define NST    16
#define RK     6
#define KDIR   4
#define LLEN   4096   // H*W
#define BB     2
#define BP_TOT 8192   // B*L
#define SCH    128    // scan chunks per (b,k)
#define TCH    32     // steps per chunk (L/SCH)

// ---------------------------------------------------------------------------
// K1: in_proj. 1024 blocks x 192 thr, 8 positions/block.
__global__ __launch_bounds__(192) void k_inproj(const float* __restrict__ x,
                                                const float* __restrict__ Wp,
                                                float* __restrict__ xi,
                                                float* __restrict__ z)
{
    __shared__ float xs[8 * 96];
    const int t  = threadIdx.x;
    const int p0 = blockIdx.x * 8;
    for (int idx = t; idx < 768; idx += 192)
        xs[idx] = x[(size_t)p0 * 96 + idx];
    __syncthreads();

    float acc0[8], acc1[8];
    #pragma unroll
    for (int i = 0; i < 8; ++i) { acc0[i] = 0.f; acc1[i] = 0.f; }
    const float* w0p = Wp + (size_t)t * 96;
    const float* w1p = Wp + (size_t)(t + 192) * 96;
    for (int k = 0; k < 96; k += 4) {
        float4 w0 = *(const float4*)(w0p + k);
        float4 w1 = *(const float4*)(w1p + k);
        #pragma unroll
        for (int p = 0; p < 8; ++p) {
            float4 xv = *(const float4*)&xs[p * 96 + k];
            acc0[p] = fmaf(w0.x, xv.x, fmaf(w0.y, xv.y, fmaf(w0.z, xv.z, fmaf(w0.w, xv.w, acc0[p]))));
            acc1[p] = fmaf(w1.x, xv.x, fmaf(w1.y, xv.y, fmaf(w1.z, xv.z, fmaf(w1.w, xv.w, acc1[p]))));
        }
    }
    #pragma unroll
    for (int p = 0; p < 8; ++p) {
        xi[(size_t)(p0 + p) * 192 + t] = acc0[p];
        z [(size_t)(p0 + p) * 192 + t] = acc1[p];
    }
}

// ---------------------------------------------------------------------------
__device__ __forceinline__ int inv_perm(int kd, int p)
{
    if (kd == 0) return p;
    if (kd == 1) return ((p & 63) << 6) | (p >> 6);
    if (kd == 2) return 4095 - p;
    return 4095 - (((p & 63) << 6) | (p >> 6));
}

__device__ __forceinline__ int perm_pos(int k, int l)
{
    if (k == 0) return l;
    if (k == 1) return ((l & 63) << 6) | (l >> 6);
    if (k == 2) return 4095 - l;
    int lr = 4095 - l;
    return ((lr & 63) << 6) | (lr >> 6);
}

__device__ __forceinline__ float softplus_fast(float x)
{
    float r = __logf(1.f + __expf(x));
    return (x > 15.f) ? x : r;
}

// binary power chain: aa[n] = e1^(n+1)
__device__ __forceinline__ void pow_chain(float e1, float* aa)
{
    float e2 = e1 * e1, e4 = e2 * e2, e8 = e4 * e4, e16 = e8 * e8;
    float e3 = e2 * e1, e5 = e4 * e1, e6 = e4 * e2, e7 = e4 * e3;
    aa[0] = e1;  aa[1] = e2;  aa[2] = e3;  aa[3] = e4;
    aa[4] = e5;  aa[5] = e6;  aa[6] = e7;  aa[7] = e8;
    aa[8] = e8 * e1;  aa[9] = e8 * e2;  aa[10] = e8 * e3;  aa[11] = e8 * e4;
    aa[12] = e8 * e5; aa[13] = e8 * e6; aa[14] = e8 * e7;  aa[15] = e16;
}

// scan-kernel LDS layout per step (stride 40): B[0..15], C[16..31], dt[32..37]
__device__ __forceinline__ int sm_remap(int c)  // src col c: 0..5 dt, 6..21 B, 22..37 C
{
    return (c < 6) ? (32 + c) : (c - 6);
}

// ---------------------------------------------------------------------------
// K2: fused depthwise conv(3x3)+SiLU + x_proj GEMM (scan-ordered out).
// Block = 8 consecutive row-major positions (same image row). Conv halo kept
// in registers; conv output goes to xc (for the scan's u) AND straight into
// the GEMM's LDS tile. Boundary branches are block-uniform (no divergence).
__global__ __launch_bounds__(192) void k_convxdbl(const float* __restrict__ xi,
                                                  const float* __restrict__ cw,
                                                  const float* __restrict__ cb,
                                                  const float* __restrict__ xpw,
                                                  float* __restrict__ xc,
                                                  float* __restrict__ xdk)
{
    __shared__ float xs[8 * 192];
    const int t   = threadIdx.x;
    const int p0  = blockIdx.x * 8;
    const int b   = p0 >> 12;
    const int pp0 = p0 & 4095;
    const int row = pp0 >> 6, c0 = pp0 & 63;

    float w9[9];
    #pragma unroll
    for (int i = 0; i < 9; ++i) w9[i] = cw[t * 9 + i];
    const float cbias = cb[t];

    float xv[3][10];
    #pragma unroll
    for (int ky = 0; ky < 3; ++ky) {
        int rr = row + ky - 1;
        #pragma unroll
        for (int kx = 0; kx < 10; ++kx) {
            int cc = c0 + kx - 1;
            float v = 0.f;
            if (rr >= 0 && rr < 64 && cc >= 0 && cc < 64)
                v = xi[((size_t)b * 4096 + rr * 64 + cc) * 192 + t];
            xv[ky][kx] = v;
        }
    }
    #pragma unroll
    for (int p = 0; p < 8; ++p) {
        float s = cbias;
        #pragma unroll
        for (int ky = 0; ky < 3; ++ky)
            #pragma unroll
            for (int kx = 0; kx < 3; ++kx)
                s = fmaf(xv[ky][p + kx], w9[ky * 3 + kx], s);
        float sv = s * (1.f / (1.f + __expf(-s)));   // SiLU
        xc[(size_t)(p0 + p) * 192 + t] = sv;
        xs[p * 192 + t] = sv;
    }
    __syncthreads();
    if (t >= 152) return;

    const int kd = t / 38, r = t % 38;
    float acc[8];
    #pragma unroll
    for (int i = 0; i < 8; ++i) acc[i] = 0.f;
    const float* wr = xpw + (size_t)t * 192;
    for (int k = 0; k < 192; k += 4) {
        float4 w = *(const float4*)(wr + k);
        #pragma unroll
        for (int p = 0; p < 8; ++p) {
            float4 x4 = *(const float4*)&xs[p * 192 + k];   // wave-uniform broadcast
            acc[p] = fmaf(w.x, x4.x, fmaf(w.y, x4.y, fmaf(w.z, x4.z, fmaf(w.w, x4.w, acc[p]))));
        }
    }
    #pragma unroll
    for (int p = 0; p < 8; ++p) {
        int pp = pp0 + p;
        int l  = inv_perm(kd, pp);
        xdk[((size_t)(b * 4 + kd) * 4096 + l) * 38 + r] = acc[p];
    }
}

// ---------------------------------------------------------------------------
// K3: scan pass 1 — local recurrence from h=0. Fast path: write local y
// (C·h_loc + D·u) to this direction's private yk buffer (plain stores, no
// atomics). Both paths: store h_end and prodA[n]=exp(A[n]*sum_delta).
__global__ __launch_bounds__(192) void k_scan1(const float* __restrict__ xc,
                                               const float* __restrict__ xdk,
                                               const float* __restrict__ dtw,
                                               const float* __restrict__ dtb,
                                               const float* __restrict__ Alog,
                                               const float* __restrict__ Ds,
                                               float* __restrict__ hend,
                                               float* __restrict__ prodA,
                                               float* __restrict__ yk)
{
    __shared__ float sm[TCH * 40];
    const int t   = threadIdx.x;
    const int blk = blockIdx.x;
    const int s = blk & (SCH - 1), k = (blk >> 7) & 3, b = blk >> 9;
    const int kd = k * 192 + t;
    const int l0 = s * TCH;

    const float* src = xdk + ((size_t)(b * 4 + k) * 4096 + l0) * 38;
    for (int idx = t; idx < TCH * 38; idx += 192) {
        int st = idx / 38, c = idx % 38;
        sm[st * 40 + sm_remap(c)] = src[idx];
    }

    const float A0 = -__expf(Alog[kd * 16]);
    bool fast = true;
    #pragma unroll
    for (int n = 1; n < 16; ++n) {
        float An = -__expf(Alog[kd * 16 + n]);
        fast = fast && (fabsf(An - (float)(n + 1) * A0) <= 1e-3f * fabsf(An));
    }
    float wdt[6];
    #pragma unroll
    for (int r = 0; r < 6; ++r) wdt[r] = dtw[kd * 6 + r];
    const float bias = dtb[kd];
    const float Dk   = Ds[kd];

    float h[16];
    #pragma unroll
    for (int n = 0; n < 16; ++n) h[n] = 0.f;
    float cd = 0.f;

    const float* xcb = xc + (size_t)b * 4096 * 192;
    float* ykb = yk + (size_t)(b * 4 + k) * 4096 * 192;
    int allfast = __syncthreads_and((int)fast);

    int p_cur = perm_pos(k, l0);
    float u = xcb[(size_t)p_cur * 192 + t];

    if (allfast) {
        for (int st = 0; st < TCH; ++st) {
            int p_next = (st + 1 < TCH) ? perm_pos(k, l0 + st + 1) : p_cur;
            float u_next = xcb[(size_t)p_next * 192 + t];
            const float* r = &sm[st * 40];
            float4 dq = *(const float4*)(r + 32);
            float xv = bias + dq.x * wdt[0] + dq.y * wdt[1] + dq.z * wdt[2]
                            + dq.w * wdt[3] + r[36] * wdt[4] + r[37] * wdt[5];
            float delta = softplus_fast(xv);
            cd += delta;
            float du = delta * u;
            float aa[16];
            pow_chain(__expf(delta * A0), aa);
            float4 b0 = *(const float4*)(r),      b1 = *(const float4*)(r + 4);
            float4 b2 = *(const float4*)(r + 8),  b3 = *(const float4*)(r + 12);
            float4 c0 = *(const float4*)(r + 16), c1 = *(const float4*)(r + 20);
            float4 c2 = *(const float4*)(r + 24), c3 = *(const float4*)(r + 28);
            float bv[16] = {b0.x, b0.y, b0.z, b0.w, b1.x, b1.y, b1.z, b1.w,
                            b2.x, b2.y, b2.z, b2.w, b3.x, b3.y, b3.z, b3.w};
            float cv[16] = {c0.x, c0.y, c0.z, c0.w, c1.x, c1.y, c1.z, c1.w,
                            c2.x, c2.y, c2.z, c2.w, c3.x, c3.y, c3.z, c3.w};
            float acc = Dk * u;
            #pragma unroll
            for (int n = 0; n < 16; ++n) {
                h[n] = fmaf(h[n], aa[n], du * bv[n]);
                acc  = fmaf(h[n], cv[n], acc);
            }
            ykb[(size_t)p_cur * 192 + t] = acc;     // plain store, owner-exclusive
            u = u_next; p_cur = p_next;
        }
    } else {
        for (int st = 0; st < TCH; ++st) {
            int p_next = (st + 1 < TCH) ? perm_pos(k, l0 + st + 1) : p_cur;
            float u_next = xcb[(size_t)p_next * 192 + t];
            const float* r = &sm[st * 40];
            float xv = bias;
            #pragma unroll
            for (int j = 0; j < 6; ++j) xv += r[32 + j] * wdt[j];
            float delta = softplus_fast(xv);
            cd += delta;
            float du = delta * u;
            #pragma unroll
            for (int n = 0; n < 16; ++n) {
                float An = -__expf(Alog[kd * 16 + n]);
                h[n] = fmaf(h[n], __expf(delta * An), du * r[n]);
            }
            u = u_next; p_cur = p_next;
        }
    }

    size_t base = (size_t)blk * 3072 + t * 16;
    float ap[16];
    if (allfast) {
        pow_chain(__expf(cd * A0), ap);
    } else {
        #pragma unroll
        for (int n = 0; n < 16; ++n)
            ap[n] = __expf(-__expf(Alog[kd * 16 + n]) * cd);
    }
    #pragma unroll
    for (int i = 0; i < 4; ++i) {
        *(float4*)&hend [base + 4 * i] = make_float4(h[4*i], h[4*i+1], h[4*i+2], h[4*i+3]);
        *(float4*)&prodA[base + 4 * i] = make_float4(ap[4*i], ap[4*i+1], ap[4*i+2], ap[4*i+3]);
    }
}

// ---------------------------------------------------------------------------
// K4: scan pass 2 — parallel chunk composition. Block=(b,k,d): 16 n-chains of
// 128 chunks. 3 phases: 8-serial group compose -> 16-serial cross-group (on 16
// lanes) -> 8-serial rewalk writing h_init into prodA.
__global__ __launch_bounds__(256) void k_scan2(const float* __restrict__ hend,
                                               float* __restrict__ prodA)
{
    __shared__ float smA[256], smH[256];
    const int t = threadIdx.x;
    const int g = t >> 4, n = t & 15;
    const int bk = blockIdx.x / 192, d = blockIdx.x % 192;
    const size_t base = (size_t)bk * SCH * 3072 + d * 16 + n;

    float a_[8], h_[8];
    float A = 1.f, H = 0.f;
    #pragma unroll
    for (int i = 0; i < 8; ++i) {
        size_t rec = base + (size_t)(g * 8 + i) * 3072;
        a_[i] = prodA[rec];
        h_[i] = hend[rec];
        H = fmaf(a_[i], H, h_[i]);
        A *= a_[i];
    }
    smA[t] = A; smH[t] = H;
    __syncthreads();
    if (t < 16) {
        float carry = 0.f;
        for (int g2 = 0; g2 < 16; ++g2) {
            float ta = smA[g2 * 16 + t], th = smH[g2 * 16 + t];
            smH[g2 * 16 + t] = carry;          // exclusive carry into group g2
            carry = fmaf(ta, carry, th);
        }
    }
    __syncthreads();
    float carry = smH[t];
    #pragma unroll
    for (int i = 0; i < 8; ++i) {
        size_t rec = base + (size_t)(g * 8 + i) * 3072;
        prodA[rec] = carry;                    // h_init
        carry = fmaf(a_[i], carry, h_[i]);
    }
}

// ---------------------------------------------------------------------------
// K5: scan pass 3 — fast: stage dt+C, recompute running cd, add correction
// sum_n C[n]*h_init[n]*exp(cd*A0)^(n+1) to yk (owner-exclusive RMW).
// Slow: full replay from h_init, overwrite yk.
__global__ __launch_bounds__(192) void k_scan3(const float* __restrict__ xc,
                                               const float* __restrict__ xdk,
                                               const float* __restrict__ dtw,
                                               const float* __restrict__ dtb,
                                               const float* __restrict__ Alog,
                                               const float* __restrict__ Ds,
                                               const float* __restrict__ hinit,
                                               float* __restrict__ yk)
{
    __shared__ float sm[TCH * 40];
    const int t   = threadIdx.x;
    const int blk = blockIdx.x;
    const int s = blk & (SCH - 1), k = (blk >> 7) & 3, b = blk >> 9;
    const int kd = k * 192 + t;
    const int l0 = s * TCH;

    const float* src = xdk + ((size_t)(b * 4 + k) * 4096 + l0) * 38;
    float* ykb = yk + (size_t)(b * 4 + k) * 4096 * 192;

    const float A0 = -__expf(Alog[kd * 16]);
    bool fast = true;
    #pragma unroll
    for (int n = 1; n < 16; ++n) {
        float An = -__expf(Alog[kd * 16 + n]);
        fast = fast && (fabsf(An - (float)(n + 1) * A0) <= 1e-3f * fabsf(An));
    }
    int allfast = __syncthreads_and((int)fast);

    float hi[16];
    size_t hbase = (size_t)blk * 3072 + t * 16;
    #pragma unroll
    for (int i = 0; i < 4; ++i) {
        float4 v = *(const float4*)&hinit[hbase + 4 * i];
        hi[4*i] = v.x; hi[4*i+1] = v.y; hi[4*i+2] = v.z; hi[4*i+3] = v.w;
    }

    if (allfast) {
        if (s == 0) return;          // h_init == 0 -> correction vanishes
        // stage C (16) + dt (6) per step: sm[st*24]: C at 0..15, dt at 16..21
        for (int idx = t; idx < TCH * 22; idx += 192) {
            int st = idx / 22, c = idx % 22;
            int gcol = (c < 6) ? c : (16 + c);           // dt cols / C cols
            sm[st * 24 + ((c < 6) ? (16 + c) : (c - 6))] = src[st * 38 + gcol];
        }
        float wdt[6];
        #pragma unroll
        for (int r = 0; r < 6; ++r) wdt[r] = dtw[kd * 6 + r];
        const float bias = dtb[kd];
        __syncthreads();
        float cd = 0.f;
        for (int st = 0; st < TCH; ++st) {
            const float* r = &sm[st * 24];
            float xv = bias + r[16] * wdt[0] + r[17] * wdt[1] + r[18] * wdt[2]
                            + r[19] * wdt[3] + r[20] * wdt[4] + r[21] * wdt[5];
            cd += softplus_fast(xv);
            float aa[16];
            pow_chain(__expf(cd * A0), aa);
            float corr = 0.f;
            #pragma unroll
            for (int n = 0; n < 16; ++n)
                corr = fmaf(aa[n] * hi[n], r[n], corr);
            size_t off = (size_t)perm_pos(k, l0 + st) * 192 + t;
            ykb[off] += corr;                 // owner-exclusive RMW
        }
    } else {
        for (int idx = t; idx < TCH * 38; idx += 192) {
            int st = idx / 38, c = idx % 38;
            sm[st * 40 + sm_remap(c)] = src[idx];
        }
        __syncthreads();
        const float* xcb = xc + (size_t)b * 4096 * 192;
        float wdt[6];
        #pragma unroll
        for (int r = 0; r < 6; ++r) wdt[r] = dtw[kd * 6 + r];
        const float bias = dtb[kd];
        const float Dk   = Ds[kd];
        float h[16];
        #pragma unroll
        for (int n = 0; n < 16; ++n) h[n] = hi[n];
        int p_cur = perm_pos(k, l0);
        float u = xcb[(size_t)p_cur * 192 + t];
        for (int st = 0; st < TCH; ++st) {
            int p_next = (st + 1 < TCH) ? perm_pos(k, l0 + st + 1) : p_cur;
            float u_next = xcb[(size_t)p_next * 192 + t];
            const float* r = &sm[st * 40];
            float xv = bias;
            #pragma unroll
            for (int j = 0; j < 6; ++j) xv += r[32 + j] * wdt[j];
            float delta = softplus_fast(xv);
            float du = delta * u;
            float acc = Dk * u;
            #pragma unroll
            for (int n = 0; n < 16; ++n) {
                float An = -__expf(Alog[kd * 16 + n]);
                h[n] = fmaf(h[n], __expf(delta * An), du * r[n]);
                acc  = fmaf(h[n], r[16 + n], acc);
            }
            ykb[(size_t)p_cur * 192 + t] = acc;   // overwrite (scan1 wrote nothing)
            u = u_next; p_cur = p_next;
        }
    }
}

// ---------------------------------------------------------------------------
// K6: sum 4 direction buffers + LayerNorm + SiLU gate + out_proj.
__global__ __launch_bounds__(192) void k_lnout(const float* __restrict__ yk,
                                               const float* __restrict__ zb,
                                               const float* __restrict__ onw,
                                               const float* __restrict__ onb,
                                               const float* __restrict__ Wo,
                                               float* __restrict__ out)
{
    __shared__ float ys[1536];
    __shared__ float ps[192], pq[192];
    __shared__ float mu[8], ri[8];
    const int t   = threadIdx.x;
    const int p0  = blockIdx.x * 8;
    const int b   = p0 >> 12;
    const int pp0 = p0 & 4095;
    const size_t KSTR = (size_t)4096 * 192;

    #pragma unroll
    for (int i = 0; i < 8; ++i) {
        size_t base = ((size_t)(b * 4) * 4096 + pp0 + i) * 192 + t;
        ys[i * 192 + t] = yk[base] + yk[base + KSTR] + yk[base + 2 * KSTR] + yk[base + 3 * KSTR];
    }
    __syncthreads();

    {
        int pg = t / 24, j = t % 24;
        float s1 = 0.f, s2 = 0.f;
        #pragma unroll
        for (int m = 0; m < 8; ++m) {
            float v = ys[pg * 192 + j + 24 * m];
            s1 += v; s2 += v * v;
        }
        ps[t] = s1; pq[t] = s2;
    }
    __syncthreads();
    if (t < 8) {
        float s1 = 0.f, s2 = 0.f;
        #pragma unroll
        for (int j = 0; j < 24; ++j) { s1 += ps[t * 24 + j]; s2 += pq[t * 24 + j]; }
        float mean = s1 * (1.f / 192.f);
        float var  = s2 * (1.f / 192.f) - mean * mean;
        mu[t] = mean;
        ri[t] = rsqrtf(var + 1e-5f);
    }
    __syncthreads();

    {
        float w = onw[t], bo = onb[t];
        #pragma unroll
        for (int i = 0; i < 8; ++i) {
            float v  = ys[i * 192 + t];
            float yn = (v - mu[i]) * ri[i] * w + bo;
            float zv = zb[(size_t)(p0 + i) * 192 + t];
            float sg = 1.f / (1.f + __expf(-zv));
            ys[i * 192 + t] = yn * (zv * sg);
        }
    }
    __syncthreads();

    const int pg = t / 96, c = t % 96;
    float acc[4];
    #pragma unroll
    for (int i = 0; i < 4; ++i) acc[i] = 0.f;
    const float* wr = Wo + (size_t)c * 192;
    for (int k = 0; k < 192; k += 4) {
        float4 w = *(const float4*)(wr + k);
        #pragma unroll
        for (int i = 0; i < 4; ++i) {
            float4 xv = *(const float4*)&ys[(pg * 4 + i) * 192 + k];
            acc[i] = fmaf(w.x, xv.x, fmaf(w.y, xv.y, fmaf(w.z, xv.z, fmaf(w.w, xv.w, acc[i]))));
        }
    }
    #pragma unroll
    for (int i = 0; i < 4; ++i)
        out[(size_t)(p0 + pg * 4 + i) * 96 + c] = acc[i];
}

// ---------------------------------------------------------------------------
extern "C" void kernel_launch(void* const* d_in, const int* in_sizes, int n_in,
                              void* d_out, int out_size, void* d_ws, size_t ws_size,
                              hipStream_t stream)
{
    const float* x    = (const float*)d_in[0];
    const float* Wp   = (const float*)d_in[1];
    const float* cw   = (const float*)d_in[2];
    const float* cb   = (const float*)d_in[3];
    const float* xpw  = (const float*)d_in[4];
    const float* dtw  = (const float*)d_in[5];
    const float* dtb  = (const float*)d_in[6];
    const float* Alog = (const float*)d_in[7];
    const float* Ds   = (const float*)d_in[8];
    const float* onw  = (const float*)d_in[9];
    const float* onb  = (const float*)d_in[10];
    const float* Wo   = (const float*)d_in[11];
    float* out = (float*)d_out;

    const size_t NBP  = (size_t)BP_TOT * 192;        // 1.57M floats
    const size_t NXD  = (size_t)BB * 4 * 4096 * 38;  // 1.25M floats
    const size_t NSC  = (size_t)BB * 4 * SCH * 3072; // 3.15M floats
    float* WS    = (float*)d_ws;
    float* xibuf = WS;                  // in_proj x-branch (conv input)
    float* zb    = WS + NBP;            // gate z
    float* xc    = WS + 2 * NBP;        // conv output (scan u)
    float* xdk   = WS + 3 * NBP;        // (b,k,l,38) scan-ordered x_dbl
    float* hend  = xdk + NXD;
    float* prodA = hend + NSC;          // after scan2: h_init
    float* yk    = prodA + NSC;         // 4 per-direction y buffers (25 MB)

    k_inproj  <<<1024, 192, 0, stream>>>(x, Wp, xibuf, zb);
    k_convxdbl<<<1024, 192, 0, stream>>>(xibuf, cw, cb, xpw, xc, xdk);
    k_scan1   <<<1024, 192, 0, stream>>>(xc, xdk, dtw, dtb, Alog, Ds, hend, prodA, yk);
    k_scan2   <<<1536, 256, 0, stream>>>(hend, prodA);
    k_scan3   <<<1024, 192, 0, stream>>>(xc, xdk, dtw, dtb, Alog, Ds, prodA, yk);
    k_lnout   <<<1024, 192, 0, stream>>>(yk, zb, onw, onb, Wo, out);
}